// Round 11
// baseline (221.420 us; speedup 1.0000x reference)
//
#include <hip/hip_runtime.h>

#define NCODES 1024
#define DIM 64
#define HW 4096       // 64*64
#define CHW 262144    // 64*4096
#define NPOS 131072   // 32*64*64
#define NELEM 8388608 // 32*64*64*64
#define TAU 4e-5f

// ws layout (bytes):
//  [0..4)            float loss accumulator (atomic)
//  [4..8)            uint ambiguous-count (atomic)
//  [256..4352)       int flags[1024]
//  [8192..270336)    ushort bswz[131072]   swizzled split-bf16 codebook frags
//  [270336..274432)  float cbnorm[1024]    (round-6-identical fmaf chain)
//  [274432..798720)  uint list[131072]     ambiguous position list
#define WS_LOSS 0
#define WS_CNT 4
#define WS_FLAGS 256
#define WS_BSWZ 8192
#define WS_CBN 270336
#define WS_LIST 274432

typedef __attribute__((ext_vector_type(8))) short bf16x8;
typedef __attribute__((ext_vector_type(4))) float f32x4;
typedef __attribute__((ext_vector_type(4))) unsigned int u32x4;

__device__ __forceinline__ unsigned short f2bf(float x) {  // RNE
  unsigned u = __float_as_uint(x);
  return (unsigned short)((u + 0x7FFFu + ((u >> 16) & 1u)) >> 16);
}
__device__ __forceinline__ float bf2f(unsigned short h) {
  return __uint_as_float(((unsigned)h) << 16);
}
// monotone float->uint order map (for u64 key packing in phase B)
__device__ __forceinline__ unsigned fxf(float d) {
  unsigned u = __float_as_uint(d);
  return (u & 0x80000000u) ? ~u : (u | 0x80000000u);
}

// Prep: split codebook to bf16 hi/lo in MFMA-B-fragment order + exact cbnorm.
// Also zeroes ws[0..8192) (loss/cnt/flags) -- replaces the memset node.
__global__ __launch_bounds__(256) void vq_prep(const float* __restrict__ cb,
                                               unsigned short* __restrict__ bswz,
                                               float* __restrict__ cbn,
                                               unsigned* __restrict__ wszero) {
  int t = blockIdx.x * 256 + threadIdx.x;  // 65536 threads = (n,k)
  if (t < 2048) wszero[t] = 0u;            // bytes [0, 8192)
  int n = t >> 6, k = t & 63;
  float v = cb[n * 64 + k];
  unsigned short h = f2bf(v);
  unsigned short lo = f2bf(v - bf2f(h));
  int i = n >> 4, lmod = n & 15;
  int q = k >> 5, kr = k & 31;
  int e = ((kr >> 4) << 2) | (kr & 3);
  int l = lmod | (((kr >> 2) & 3) << 4);
  bswz[(((i * 2 + 0) * 2 + q) * 64 + l) * 8 + e] = h;
  bswz[(((i * 2 + 1) * 2 + q) * 64 + l) * 8 + e] = lo;
  if (k == 0) {  // cbnorm: bit-identical to round-6 cb_norms chain
    const float* ep = cb + n * 64;
    float s = 0.f;
#pragma unroll
    for (int c = 0; c < 64; ++c) s = fmaf(ep[c], ep[c], s);
    cbn[n] = s;
  }
}

// Phase A (round-11): 1024 blocks x 512 threads; block owns 128 positions;
// wave owns 16 (one MFMA strip). 3 independent 2-MFMA accumulator chains
// (was one 6-chain: ~150cyc dependent latency) + 8-waves/SIMD occupancy.
__global__ __launch_bounds__(512, 8) void vq_phaseA(
    const float* __restrict__ z, const float* __restrict__ cb,
    const unsigned short* __restrict__ bswz, const float* __restrict__ cbn,
    float* __restrict__ out_zq, float* __restrict__ out_idx,
    float* __restrict__ loss, unsigned* __restrict__ cnt,
    unsigned* __restrict__ list, int* __restrict__ flags) {
  const int tid = threadIdx.x, w = tid >> 6, l = tid & 63;
  const int l15 = l & 15, lg = (l >> 4) & 3;
  const int posbase = blockIdx.x * 128;
  const int b = posbase >> 12;        // uniform per block (128 | 4096)
  const int hwb = posbase & 4095;

  // A-frags: wave w owns positions posbase + w*16 + [0,16); hi/lo split,
  // same slot->k formula as vq_prep so k-map errors cancel in the dot.
  bf16x8 Ah[2], Al[2];
  {
    const float* zp = z + (size_t)b * CHW + (hwb + w * 16 + l15);
#pragma unroll
    for (int q = 0; q < 2; ++q) {
      bf16x8 ah, al;
#pragma unroll
      for (int e = 0; e < 8; ++e) {
        int c = q * 32 + ((e >> 2) << 4) + (lg << 2) + (e & 3);
        float v = zp[c * HW];
        unsigned short h = f2bf(v);
        ah[e] = (short)h;
        al[e] = (short)f2bf(v - bf2f(h));
      }
      Ah[q] = ah;
      Al[q] = al;
    }
  }

  float bd[4], b2[4];
  unsigned bi[4];
#pragma unroll
  for (int r = 0; r < 4; ++r) { bd[r] = 3.4e38f; b2[r] = 3.4e38f; bi[r] = 0; }

  const u32x4* B = (const u32x4*)bswz;
  for (int i = 0; i < 64; ++i) {  // 16 codes per iter
    bf16x8 b00 = __builtin_bit_cast(bf16x8, B[(i * 4 + 0) * 64 + l]);  // hi q0
    bf16x8 b01 = __builtin_bit_cast(bf16x8, B[(i * 4 + 1) * 64 + l]);  // hi q1
    bf16x8 b10 = __builtin_bit_cast(bf16x8, B[(i * 4 + 2) * 64 + l]);  // lo q0
    bf16x8 b11 = __builtin_bit_cast(bf16x8, B[(i * 4 + 3) * 64 + l]);  // lo q1
    float cbnv = cbn[i * 16 + l15];
    unsigned nb = (unsigned)(i * 16 + l15);
    f32x4 Ca = {0.f, 0.f, 0.f, 0.f};
    f32x4 Cb = {0.f, 0.f, 0.f, 0.f};
    f32x4 Cc = {0.f, 0.f, 0.f, 0.f};
    Ca = __builtin_amdgcn_mfma_f32_16x16x32_bf16(Ah[0], b00, Ca, 0, 0, 0);
    Cb = __builtin_amdgcn_mfma_f32_16x16x32_bf16(Ah[0], b10, Cb, 0, 0, 0);
    Cc = __builtin_amdgcn_mfma_f32_16x16x32_bf16(Al[0], b00, Cc, 0, 0, 0);
    Ca = __builtin_amdgcn_mfma_f32_16x16x32_bf16(Ah[1], b01, Ca, 0, 0, 0);
    Cb = __builtin_amdgcn_mfma_f32_16x16x32_bf16(Ah[1], b11, Cb, 0, 0, 0);
    Cc = __builtin_amdgcn_mfma_f32_16x16x32_bf16(Al[1], b01, Cc, 0, 0, 0);
#pragma unroll
    for (int r = 0; r < 4; ++r) {
      float d = fmaf(Ca[r] + (Cb[r] + Cc[r]), -2.0f, cbnv);
      bool lt = d < bd[r];
      float loser = lt ? bd[r] : d;
      b2[r] = fminf(b2[r], loser);
      bd[r] = fminf(bd[r], d);
      bi[r] = lt ? nb : bi[r];
    }
  }

  // reduce over the 16 code-lanes (xor within low 4 lane bits)
  __shared__ unsigned res[128];
#pragma unroll
  for (int r = 0; r < 4; ++r) {
    float d = bd[r], s2 = b2[r];
    unsigned idx = bi[r];
#pragma unroll
    for (int st = 1; st < 16; st <<= 1) {
      float od = __shfl_xor(d, st, 64);
      unsigned oi = __shfl_xor(idx, st, 64);
      float o2 = __shfl_xor(s2, st, 64);
      bool take = (od < d) || (od == d && oi < idx);
      float loser = take ? d : od;
      s2 = fminf(fminf(s2, o2), loser);
      d = take ? od : d;
      idx = take ? oi : idx;
    }
    if (l15 == 0) {
      res[w * 16 + lg * 4 + r] = idx | (((s2 - d) <= TAU) ? 0x80000000u : 0u);
    }
  }
  __syncthreads();

  // epilogue: 512 threads over 128 positions, 16 channels per quarter
  const int pl = tid & 127, quarter = tid >> 7;
  unsigned pk = res[pl];
  unsigned bj = pk & 1023u;
  int pos = posbase + pl;
  float lsum = 0.f;
  if (pk & 0x80000000u) {
    if (quarter == 0) {
      unsigned idx = atomicAdd(cnt, 1u);
      list[idx] = (unsigned)pos;
    }
  } else {
    if (quarter == 0) {
      out_idx[pos] = (float)bj;
      flags[bj] = 1;
    }
    const float* zp = z + (size_t)b * CHW + (pos & 4095);
    const float* eb = cb + bj * 64;
    float* op = out_zq + (size_t)b * CHW + (pos & 4095);
#pragma unroll
    for (int cc = 0; cc < 16; ++cc) {
      int c = quarter * 16 + cc;
      float zv = zp[c * HW];
      float e = eb[c];
      float diff = e - zv;
      lsum = fmaf(diff, diff, lsum);
      op[c * HW] = zv + diff;  // z + (z_q - z): reference rounding
    }
  }
  for (int off = 32; off; off >>= 1) lsum += __shfl_down(lsum, off, 64);
  __shared__ float wsum[8];
  if (l == 0) wsum[w] = lsum;
  __syncthreads();
  if (tid == 0) {
    float t2 = 0.f;
#pragma unroll
    for (int i2 = 0; i2 < 8; ++i2) t2 += wsum[i2];
    atomicAdd(loss, t2);
  }
}

// Phase B: round-6 structure over the compacted list. lane = list position,
// wave = 128-code chunk on the wave-uniform scalar-load path. Identical
// per-code FMA chain as the serial formula; u64 (dist,idx) min reproduces
// the first-min tie-break exactly. unroll 2: two independent row chains.
template <int W>
__device__ __forceinline__ void epilogue8(const float* __restrict__ eb,
                                          const float zr[DIM],
                                          float* __restrict__ op,
                                          float& lsum) {
#pragma unroll
  for (int cc = 0; cc < 8; ++cc) {
    const int c = W * 8 + cc;
    float e = eb[c];
    float diff = e - zr[c];
    lsum = fmaf(diff, diff, lsum);
    op[c * HW] = zr[c] + diff;
  }
}

__global__ __launch_bounds__(512, 2) void vq_phaseB(
    const float* __restrict__ z, const float* __restrict__ cb,
    const float* __restrict__ cbn, float* __restrict__ out_zq,
    float* __restrict__ out_idx, float* __restrict__ loss,
    const unsigned* __restrict__ cnt, const unsigned* __restrict__ list,
    int* __restrict__ flags) {
  const unsigned total = *cnt;
  const int t = threadIdx.x, w = t >> 6, l = t & 63;
  __shared__ unsigned long long keys[8][64];
  __shared__ float wsum[8];

  for (unsigned base = blockIdx.x * 64u; base < total; base += 512u * 64u) {
    const bool active = (base + (unsigned)l) < total;
    const int pos = active ? (int)list[base + l] : 0;
    const int b = pos >> 12, hw = pos & 4095;
    const float* zp = z + (size_t)b * CHW + hw;

    float zr[DIM];
#pragma unroll
    for (int c = 0; c < DIM; ++c) zr[c] = zp[c * HW];
    float A = 0.f;
#pragma unroll
    for (int c = 0; c < DIM; ++c) A = fmaf(zr[c], zr[c], A);

    const int j0 = __builtin_amdgcn_readfirstlane(w * 128);
    float best = 3.4e38f;
    int bestj = j0;
#pragma unroll 2
    for (int jj = 0; jj < 128; ++jj) {
      const int j = j0 + jj;
      const float* ej = cb + j * 64;  // wave-uniform -> scalar loads
      float d0 = 0.f, d1 = 0.f, d2 = 0.f, d3 = 0.f;
#pragma unroll
      for (int k = 0; k < 64; k += 4) {
        d0 = fmaf(zr[k + 0], ej[k + 0], d0);
        d1 = fmaf(zr[k + 1], ej[k + 1], d1);
        d2 = fmaf(zr[k + 2], ej[k + 2], d2);
        d3 = fmaf(zr[k + 3], ej[k + 3], d3);
      }
      float dot = (d0 + d1) + (d2 + d3);
      float dist = (A + cbn[j]) - 2.0f * dot;
      if (dist < best) { best = dist; bestj = j; }
    }

    __syncthreads();  // protect keys/wsum reuse across grid-stride iters
    keys[w][l] = ((unsigned long long)fxf(best) << 32) | (unsigned)bestj;
    __syncthreads();
    unsigned long long km = keys[0][l];
#pragma unroll
    for (int ww = 1; ww < 8; ++ww) {
      unsigned long long k2 = keys[ww][l];
      km = km < k2 ? km : k2;
    }
    const unsigned bj = (unsigned)(km & 0xFFFFFFFFull);

    float lsum = 0.f;
    if (active) {
      const float* eb = cb + bj * 64;
      float* op = out_zq + (size_t)b * CHW + hw;
      if (w == 0)      epilogue8<0>(eb, zr, op, lsum);
      else if (w == 1) epilogue8<1>(eb, zr, op, lsum);
      else if (w == 2) epilogue8<2>(eb, zr, op, lsum);
      else if (w == 3) epilogue8<3>(eb, zr, op, lsum);
      else if (w == 4) epilogue8<4>(eb, zr, op, lsum);
      else if (w == 5) epilogue8<5>(eb, zr, op, lsum);
      else if (w == 6) epilogue8<6>(eb, zr, op, lsum);
      else             epilogue8<7>(eb, zr, op, lsum);
      if (w == 0) {
        out_idx[pos] = (float)bj;
        flags[bj] = 1;
      }
    }
    for (int off = 32; off; off >>= 1) lsum += __shfl_down(lsum, off, 64);
    if (l == 0) wsum[w] = lsum;
    __syncthreads();
    if (t == 0) {
      float t2 = 0.f;
#pragma unroll
      for (int i2 = 0; i2 < 8; ++i2) t2 += wsum[i2];
      atomicAdd(loss, t2);
    }
  }
}

__global__ __launch_bounds__(1024) void vq_finalize(
    const int* __restrict__ flags, const float* __restrict__ loss,
    float* __restrict__ out_scalars) {
  __shared__ int cnt_[16];
  int t = threadIdx.x;
  int f = flags[t];
  for (int off = 32; off; off >>= 1) f += __shfl_down(f, off, 64);
  int lane = t & 63, wid = t >> 6;
  if (lane == 0) cnt_[wid] = f;
  __syncthreads();
  if (t == 0) {
    int c = 0;
#pragma unroll
    for (int i = 0; i < 16; ++i) c += cnt_[i];
    out_scalars[0] = 1.25f * (*loss) / (float)NELEM;  // vq_loss
    out_scalars[1] = (float)c / (float)NCODES;        // usage
  }
}

extern "C" void kernel_launch(void* const* d_in, const int* in_sizes, int n_in,
                              void* d_out, int out_size, void* d_ws, size_t ws_size,
                              hipStream_t stream) {
  const float* z = (const float*)d_in[0];
  const float* cb = (const float*)d_in[1];
  float* out = (float*)d_out;

  char* ws = (char*)d_ws;
  float* loss = (float*)(ws + WS_LOSS);
  unsigned* cnt = (unsigned*)(ws + WS_CNT);
  int* flags = (int*)(ws + WS_FLAGS);
  unsigned short* bswz = (unsigned short*)(ws + WS_BSWZ);
  float* cbn = (float*)(ws + WS_CBN);
  unsigned* list = (unsigned*)(ws + WS_LIST);

  vq_prep<<<256, 256, 0, stream>>>(cb, bswz, cbn, (unsigned*)d_ws);
  vq_phaseA<<<1024, 512, 0, stream>>>(z, cb, bswz, cbn, out, out + NELEM + 2,
                                      loss, cnt, list, flags);
  vq_phaseB<<<512, 512, 0, stream>>>(z, cb, cbn, out, out + NELEM + 2, loss,
                                     cnt, list, flags);
  vq_finalize<<<1, NCODES, 0, stream>>>(flags, loss, out + NELEM);
}